// Round 2
// baseline (321.319 us; speedup 1.0000x reference)
//
#include <hip/hip_runtime.h>
#include <hip/hip_bf16.h>
#include <math.h>

#define NSTR 4
#define DEMB 1024
#define KDIM 4096
#define CTOT 24
#define NTOK 8192
#define EPSF 1.1920928955078125e-07f

typedef __attribute__((ext_vector_type(8))) short short8;
typedef __attribute__((ext_vector_type(4))) float f32x4;

__device__ __forceinline__ short8 pack8(float4 a, float4 b) {
    union { short8 s; __hip_bfloat162 h[4]; } u;
    u.h[0] = __float22bfloat162_rn(float2{a.x, a.y});
    u.h[1] = __float22bfloat162_rn(float2{a.z, a.w});
    u.h[2] = __float22bfloat162_rn(float2{b.x, b.y});
    u.h[3] = __float22bfloat162_rn(float2{b.z, b.w});
    return u.s;
}

// ---------- Fully fused: MFMA raw -> gate/sinkhorn (LDS) -> mix -------------
// 512 blocks x 16 tokens, 256 threads (4 waves). Phase A: waves split K
// (1024 each), bf16 MFMA for raw[c], f32 FMA for ss; LDS cross-wave reduce;
// 16 threads run gate+sinkhorn, h[16][24] stays in LDS. Phase B: wave w
// mixes tokens w*4..w*4+3, re-reading state from global — those lines were
// streamed by THIS block ~20us ago, so they hit L2/L3, not HBM.
__global__ __launch_bounds__(256, 2) void k_fused(
    const float* __restrict__ state,
    const float* __restrict__ residual,
    const float* __restrict__ W,
    const float* __restrict__ alpha,
    const float* __restrict__ bias,
    float* __restrict__ out)
{
    const int tid = threadIdx.x;
    const int w = tid >> 6, lane = tid & 63, q = lane >> 4, mn = lane & 15;
    const int tok0 = blockIdx.x * 16;
    const int k0 = w * 1024 + q * 8;

    const float* Ap  = state + (size_t)(tok0 + mn) * KDIM + k0;
    const float* Bp0 = W + (size_t)mn * KDIM + k0;
    int r1 = 16 + mn; if (r1 > 23) r1 = 23;     // clamp: cols 24..31 unused
    const float* Bp1 = W + (size_t)r1 * KDIM + k0;

    f32x4 acc0 = {0.f, 0.f, 0.f, 0.f};
    f32x4 acc1 = {0.f, 0.f, 0.f, 0.f};
    float ss = 0.f;

#pragma unroll 2
    for (int s = 0; s < 32; ++s) {
        const int off = s * 32;
        const float4 a0  = *(const float4*)(Ap + off);
        const float4 a1  = *(const float4*)(Ap + off + 4);
        const float4 b00 = *(const float4*)(Bp0 + off);
        const float4 b01 = *(const float4*)(Bp0 + off + 4);
        const float4 b10 = *(const float4*)(Bp1 + off);
        const float4 b11 = *(const float4*)(Bp1 + off + 4);
        ss += a0.x*a0.x + a0.y*a0.y + a0.z*a0.z + a0.w*a0.w
            + a1.x*a1.x + a1.y*a1.y + a1.z*a1.z + a1.w*a1.w;
        const short8 af  = pack8(a0, a1);
        const short8 bf0 = pack8(b00, b01);
        const short8 bf1 = pack8(b10, b11);
        acc0 = __builtin_amdgcn_mfma_f32_16x16x32_bf16(af, bf0, acc0, 0, 0, 0);
        acc1 = __builtin_amdgcn_mfma_f32_16x16x32_bf16(af, bf1, acc1, 0, 0, 0);
    }

    __shared__ float part[4][16][28];   // [wave][token][c] (+pad)
    __shared__ float ssb[4][4][16];     // [wave][quad][token]
    __shared__ float h_lds[16][24];     // per-token gates (row = 96B, 16B-aligned)
#pragma unroll
    for (int r = 0; r < 4; ++r) part[w][q * 4 + r][mn] = acc0[r];
    if (mn < 8) {
#pragma unroll
        for (int r = 0; r < 4; ++r) part[w][q * 4 + r][16 + mn] = acc1[r];
    }
    ssb[w][q][mn] = ss;
    __syncthreads();

    // Gate + sinkhorn: one thread per token (16 of 256). ~1us serial chain;
    // the co-resident second block fills the CU meanwhile.
    if (tid < 16) {
        const int t = tid;
        float r[24];
#pragma unroll
        for (int c = 0; c < 24; ++c)
            r[c] = part[0][t][c] + part[1][t][c] + part[2][t][c] + part[3][t][c];
        float sssum = 0.f;
#pragma unroll
        for (int ww = 0; ww < 4; ++ww)
#pragma unroll
            for (int qq = 0; qq < 4; ++qq) sssum += ssb[ww][qq][t];

        const float scale = rsqrtf(sssum * (1.f / KDIM) + EPSF);
        const float a0 = alpha[0], a1 = alpha[1], a2 = alpha[2];
#pragma unroll
        for (int n = 0; n < 4; ++n) {
            float x = a0 * (r[n] * scale) + bias[n];
            h_lds[t][n] = 1.f / (1.f + __expf(-x));
        }
#pragma unroll
        for (int n = 0; n < 4; ++n) {
            float x = a1 * (r[4 + n] * scale) + bias[4 + n];
            h_lds[t][4 + n] = 2.f / (1.f + __expf(-x));
        }
        float m[16];
#pragma unroll
        for (int e = 0; e < 16; ++e) {
            float x = a2 * (r[8 + e] * scale) + bias[8 + e];
            x = fminf(fmaxf(x, -20.f), 20.f);
            m[e] = __expf(x);
        }
#pragma unroll
        for (int it = 0; it < 10; ++it) {
#pragma unroll
            for (int jj = 0; jj < 4; ++jj) {
                float cs = m[jj] + m[4 + jj] + m[8 + jj] + m[12 + jj];
                float inv = __builtin_amdgcn_rcpf(fmaxf(cs, 1e-12f));
                m[jj] *= inv; m[4 + jj] *= inv; m[8 + jj] *= inv; m[12 + jj] *= inv;
            }
#pragma unroll
            for (int ii = 0; ii < 4; ++ii) {
                float rs = m[4*ii] + m[4*ii+1] + m[4*ii+2] + m[4*ii+3];
                float inv = __builtin_amdgcn_rcpf(fmaxf(rs, 1e-12f));
                m[4*ii] *= inv; m[4*ii+1] *= inv; m[4*ii+2] *= inv; m[4*ii+3] *= inv;
            }
        }
#pragma unroll
        for (int e = 0; e < 16; ++e) h_lds[t][8 + e] = m[e];
    }
    __syncthreads();

    // ---------------- Phase B: mix. Wave w owns tokens w*4 .. w*4+3. --------
#pragma unroll 1
    for (int tt = 0; tt < 4; ++tt) {
        const int t = w * 4 + tt;
        const int token = tok0 + t;

        const float4 h03 = *(const float4*)&h_lds[t][0];    // h_pre
        const float4 h47 = *(const float4*)&h_lds[t][4];    // h_post
        const float4 hr0 = *(const float4*)&h_lds[t][8];    // h_res rows
        const float4 hr1 = *(const float4*)&h_lds[t][12];
        const float4 hr2 = *(const float4*)&h_lds[t][16];
        const float4 hr3 = *(const float4*)&h_lds[t][20];

        const float4* sp = (const float4*)(state + (size_t)token * KDIM);
        const float4* rp = (const float4*)(residual + (size_t)token * DEMB);
        float4* pre_p = (float4*)(out + (size_t)token * DEMB);
        float4* ns_p  = (float4*)(out + (size_t)NTOK * DEMB + (size_t)token * KDIM);

#pragma unroll
        for (int dc = 0; dc < 4; ++dc) {
            const int idx = dc * 64 + lane;     // float4 index within DEMB
            const float4 x0 = sp[idx];
            const float4 x1 = sp[256 + idx];
            const float4 x2 = sp[512 + idx];
            const float4 x3 = sp[768 + idx];
            const float4 rr = rp[idx];

            float4 pre;
            pre.x = h03.x*x0.x + h03.y*x1.x + h03.z*x2.x + h03.w*x3.x;
            pre.y = h03.x*x0.y + h03.y*x1.y + h03.z*x2.y + h03.w*x3.y;
            pre.z = h03.x*x0.z + h03.y*x1.z + h03.z*x2.z + h03.w*x3.z;
            pre.w = h03.x*x0.w + h03.y*x1.w + h03.z*x2.w + h03.w*x3.w;
            pre_p[idx] = pre;

            float4 o0;
            o0.x = hr0.x*x0.x + hr0.y*x1.x + hr0.z*x2.x + hr0.w*x3.x + h47.x*rr.x;
            o0.y = hr0.x*x0.y + hr0.y*x1.y + hr0.z*x2.y + hr0.w*x3.y + h47.x*rr.y;
            o0.z = hr0.x*x0.z + hr0.y*x1.z + hr0.z*x2.z + hr0.w*x3.z + h47.x*rr.z;
            o0.w = hr0.x*x0.w + hr0.y*x1.w + hr0.z*x2.w + hr0.w*x3.w + h47.x*rr.w;
            ns_p[idx] = o0;

            float4 o1;
            o1.x = hr1.x*x0.x + hr1.y*x1.x + hr1.z*x2.x + hr1.w*x3.x + h47.y*rr.x;
            o1.y = hr1.x*x0.y + hr1.y*x1.y + hr1.z*x2.y + hr1.w*x3.y + h47.y*rr.y;
            o1.z = hr1.x*x0.z + hr1.y*x1.z + hr1.z*x2.z + hr1.w*x3.z + h47.y*rr.z;
            o1.w = hr1.x*x0.w + hr1.y*x1.w + hr1.z*x2.w + hr1.w*x3.w + h47.y*rr.w;
            ns_p[256 + idx] = o1;

            float4 o2;
            o2.x = hr2.x*x0.x + hr2.y*x1.x + hr2.z*x2.x + hr2.w*x3.x + h47.z*rr.x;
            o2.y = hr2.x*x0.y + hr2.y*x1.y + hr2.z*x2.y + hr2.w*x3.y + h47.z*rr.y;
            o2.z = hr2.x*x0.z + hr2.y*x1.z + hr2.z*x2.z + hr2.w*x3.z + h47.z*rr.z;
            o2.w = hr2.x*x0.w + hr2.y*x1.w + hr2.z*x2.w + hr2.w*x3.w + h47.z*rr.w;
            ns_p[512 + idx] = o2;

            float4 o3;
            o3.x = hr3.x*x0.x + hr3.y*x1.x + hr3.z*x2.x + hr3.w*x3.x + h47.w*rr.x;
            o3.y = hr3.x*x0.y + hr3.y*x1.y + hr3.z*x2.y + hr3.w*x3.y + h47.w*rr.y;
            o3.z = hr3.x*x0.z + hr3.y*x1.z + hr3.z*x2.z + hr3.w*x3.z + h47.w*rr.z;
            o3.w = hr3.x*x0.w + hr3.y*x1.w + hr3.z*x2.w + hr3.w*x3.w + h47.w*rr.w;
            ns_p[768 + idx] = o3;
        }
    }
}

extern "C" void kernel_launch(void* const* d_in, const int* in_sizes, int n_in,
                              void* d_out, int out_size, void* d_ws, size_t ws_size,
                              hipStream_t stream) {
    const float* state    = (const float*)d_in[0];
    const float* residual = (const float*)d_in[1];
    const float* W        = (const float*)d_in[2];
    const float* alpha    = (const float*)d_in[3];
    const float* bias     = (const float*)d_in[4];
    float* out = (float*)d_out;
    // d_ws unused: gates live in LDS; no intermediate global traffic at all.

    hipLaunchKernelGGL(k_fused, dim3(NTOK / 16), dim3(256), 0, stream,
                       state, residual, W, alpha, bias, out);
}

// Round 3
// 309.897 us; speedup vs baseline: 1.0369x; 1.0369x over previous
//
#include <hip/hip_runtime.h>
#include <hip/hip_bf16.h>
#include <math.h>

#define NSTR 4
#define DEMB 1024
#define KDIM 4096
#define CTOT 24
#define NTOK 8192
#define EPSF 1.1920928955078125e-07f

typedef __attribute__((ext_vector_type(8))) short short8;
typedef __attribute__((ext_vector_type(4))) float f32x4;

__device__ __forceinline__ short8 pack8(float4 a, float4 b) {
    union { short8 s; __hip_bfloat162 h[4]; } u;
    u.h[0] = __float22bfloat162_rn(float2{a.x, a.y});
    u.h[1] = __float22bfloat162_rn(float2{a.z, a.w});
    u.h[2] = __float22bfloat162_rn(float2{b.x, b.y});
    u.h[3] = __float22bfloat162_rn(float2{b.z, b.w});
    return u.s;
}

// ---------- Fully fused: MFMA raw -> gate/sinkhorn (LDS) -> mix -------------
// 512 blocks x 16 tokens, 512 threads (8 waves). R2 post-mortem: 256-thr
// blocks capped occupancy at 8 waves/CU (19.6%) -> 2.6 TB/s, latency-bound.
// 8 waves split K (512 each) -> 16 waves/CU (2 blocks/CU via launch_bounds).
// Phase B: wave w mixes tokens w*2..w*2+1; state re-read hits L3 (proven R2:
// FETCH 153 MB ~= ideal).
__global__ __launch_bounds__(512, 4) void k_fused(
    const float* __restrict__ state,
    const float* __restrict__ residual,
    const float* __restrict__ W,
    const float* __restrict__ alpha,
    const float* __restrict__ bias,
    float* __restrict__ out)
{
    const int tid = threadIdx.x;
    const int w = tid >> 6, lane = tid & 63, q = lane >> 4, mn = lane & 15;
    const int tok0 = blockIdx.x * 16;
    const int k0 = w * 512 + q * 8;

    const float* Ap  = state + (size_t)(tok0 + mn) * KDIM + k0;
    const float* Bp0 = W + (size_t)mn * KDIM + k0;
    int r1 = 16 + mn; if (r1 > 23) r1 = 23;     // clamp: cols 24..31 unused
    const float* Bp1 = W + (size_t)r1 * KDIM + k0;

    f32x4 acc0 = {0.f, 0.f, 0.f, 0.f};
    f32x4 acc1 = {0.f, 0.f, 0.f, 0.f};
    float ss = 0.f;

#pragma unroll 2
    for (int s = 0; s < 16; ++s) {
        const int off = s * 32;
        const float4 a0  = *(const float4*)(Ap + off);
        const float4 a1  = *(const float4*)(Ap + off + 4);
        const float4 b00 = *(const float4*)(Bp0 + off);
        const float4 b01 = *(const float4*)(Bp0 + off + 4);
        const float4 b10 = *(const float4*)(Bp1 + off);
        const float4 b11 = *(const float4*)(Bp1 + off + 4);
        ss += a0.x*a0.x + a0.y*a0.y + a0.z*a0.z + a0.w*a0.w
            + a1.x*a1.x + a1.y*a1.y + a1.z*a1.z + a1.w*a1.w;
        const short8 af  = pack8(a0, a1);
        const short8 bf0 = pack8(b00, b01);
        const short8 bf1 = pack8(b10, b11);
        acc0 = __builtin_amdgcn_mfma_f32_16x16x32_bf16(af, bf0, acc0, 0, 0, 0);
        acc1 = __builtin_amdgcn_mfma_f32_16x16x32_bf16(af, bf1, acc1, 0, 0, 0);
    }

    __shared__ float part[8][16][28];   // [wave][token][c] (+pad)
    __shared__ float ssb[8][4][16];     // [wave][quad][token]
    __shared__ float h_lds[16][24];     // per-token gates (row = 96B)
#pragma unroll
    for (int r = 0; r < 4; ++r) part[w][q * 4 + r][mn] = acc0[r];
    if (mn < 8) {
#pragma unroll
        for (int r = 0; r < 4; ++r) part[w][q * 4 + r][16 + mn] = acc1[r];
    }
    ssb[w][q][mn] = ss;
    __syncthreads();

    // Gate + sinkhorn: one thread per token (16 of 512). ~1us serial chain;
    // the co-resident second block fills the CU meanwhile.
    if (tid < 16) {
        const int t = tid;
        float r[24];
#pragma unroll
        for (int c = 0; c < 24; ++c) {
            float v = 0.f;
#pragma unroll
            for (int ww = 0; ww < 8; ++ww) v += part[ww][t][c];
            r[c] = v;
        }
        float sssum = 0.f;
#pragma unroll
        for (int ww = 0; ww < 8; ++ww)
#pragma unroll
            for (int qq = 0; qq < 4; ++qq) sssum += ssb[ww][qq][t];

        const float scale = rsqrtf(sssum * (1.f / KDIM) + EPSF);
        const float a0 = alpha[0], a1 = alpha[1], a2 = alpha[2];
#pragma unroll
        for (int n = 0; n < 4; ++n) {
            float x = a0 * (r[n] * scale) + bias[n];
            h_lds[t][n] = 1.f / (1.f + __expf(-x));
        }
#pragma unroll
        for (int n = 0; n < 4; ++n) {
            float x = a1 * (r[4 + n] * scale) + bias[4 + n];
            h_lds[t][4 + n] = 2.f / (1.f + __expf(-x));
        }
        float m[16];
#pragma unroll
        for (int e = 0; e < 16; ++e) {
            float x = a2 * (r[8 + e] * scale) + bias[8 + e];
            x = fminf(fmaxf(x, -20.f), 20.f);
            m[e] = __expf(x);
        }
#pragma unroll
        for (int it = 0; it < 10; ++it) {
#pragma unroll
            for (int jj = 0; jj < 4; ++jj) {
                float cs = m[jj] + m[4 + jj] + m[8 + jj] + m[12 + jj];
                float inv = __builtin_amdgcn_rcpf(fmaxf(cs, 1e-12f));
                m[jj] *= inv; m[4 + jj] *= inv; m[8 + jj] *= inv; m[12 + jj] *= inv;
            }
#pragma unroll
            for (int ii = 0; ii < 4; ++ii) {
                float rs = m[4*ii] + m[4*ii+1] + m[4*ii+2] + m[4*ii+3];
                float inv = __builtin_amdgcn_rcpf(fmaxf(rs, 1e-12f));
                m[4*ii] *= inv; m[4*ii+1] *= inv; m[4*ii+2] *= inv; m[4*ii+3] *= inv;
            }
        }
#pragma unroll
        for (int e = 0; e < 16; ++e) h_lds[t][8 + e] = m[e];
    }
    __syncthreads();

    // ---------------- Phase B: mix. Wave w owns tokens w*2, w*2+1. ----------
#pragma unroll 1
    for (int tt = 0; tt < 2; ++tt) {
        const int t = w * 2 + tt;
        const int token = tok0 + t;

        const float4 h03 = *(const float4*)&h_lds[t][0];    // h_pre
        const float4 h47 = *(const float4*)&h_lds[t][4];    // h_post
        const float4 hr0 = *(const float4*)&h_lds[t][8];    // h_res rows
        const float4 hr1 = *(const float4*)&h_lds[t][12];
        const float4 hr2 = *(const float4*)&h_lds[t][16];
        const float4 hr3 = *(const float4*)&h_lds[t][20];

        const float4* sp = (const float4*)(state + (size_t)token * KDIM);
        const float4* rp = (const float4*)(residual + (size_t)token * DEMB);
        float4* pre_p = (float4*)(out + (size_t)token * DEMB);
        float4* ns_p  = (float4*)(out + (size_t)NTOK * DEMB + (size_t)token * KDIM);

#pragma unroll
        for (int dc = 0; dc < 4; ++dc) {
            const int idx = dc * 64 + lane;     // float4 index within DEMB
            const float4 x0 = sp[idx];
            const float4 x1 = sp[256 + idx];
            const float4 x2 = sp[512 + idx];
            const float4 x3 = sp[768 + idx];
            const float4 rr = rp[idx];

            float4 pre;
            pre.x = h03.x*x0.x + h03.y*x1.x + h03.z*x2.x + h03.w*x3.x;
            pre.y = h03.x*x0.y + h03.y*x1.y + h03.z*x2.y + h03.w*x3.y;
            pre.z = h03.x*x0.z + h03.y*x1.z + h03.z*x2.z + h03.w*x3.z;
            pre.w = h03.x*x0.w + h03.y*x1.w + h03.z*x2.w + h03.w*x3.w;
            pre_p[idx] = pre;

            float4 o0;
            o0.x = hr0.x*x0.x + hr0.y*x1.x + hr0.z*x2.x + hr0.w*x3.x + h47.x*rr.x;
            o0.y = hr0.x*x0.y + hr0.y*x1.y + hr0.z*x2.y + hr0.w*x3.y + h47.x*rr.y;
            o0.z = hr0.x*x0.z + hr0.y*x1.z + hr0.z*x2.z + hr0.w*x3.z + h47.x*rr.z;
            o0.w = hr0.x*x0.w + hr0.y*x1.w + hr0.z*x2.w + hr0.w*x3.w + h47.x*rr.w;
            ns_p[idx] = o0;

            float4 o1;
            o1.x = hr1.x*x0.x + hr1.y*x1.x + hr1.z*x2.x + hr1.w*x3.x + h47.y*rr.x;
            o1.y = hr1.x*x0.y + hr1.y*x1.y + hr1.z*x2.y + hr1.w*x3.y + h47.y*rr.y;
            o1.z = hr1.x*x0.z + hr1.y*x1.z + hr1.z*x2.z + hr1.w*x3.z + h47.y*rr.z;
            o1.w = hr1.x*x0.w + hr1.y*x1.w + hr1.z*x2.w + hr1.w*x3.w + h47.y*rr.w;
            ns_p[256 + idx] = o1;

            float4 o2;
            o2.x = hr2.x*x0.x + hr2.y*x1.x + hr2.z*x2.x + hr2.w*x3.x + h47.z*rr.x;
            o2.y = hr2.x*x0.y + hr2.y*x1.y + hr2.z*x2.y + hr2.w*x3.y + h47.z*rr.y;
            o2.z = hr2.x*x0.z + hr2.y*x1.z + hr2.z*x2.z + hr2.w*x3.z + h47.z*rr.z;
            o2.w = hr2.x*x0.w + hr2.y*x1.w + hr2.z*x2.w + hr2.w*x3.w + h47.z*rr.w;
            ns_p[512 + idx] = o2;

            float4 o3;
            o3.x = hr3.x*x0.x + hr3.y*x1.x + hr3.z*x2.x + hr3.w*x3.x + h47.w*rr.x;
            o3.y = hr3.x*x0.y + hr3.y*x1.y + hr3.z*x2.y + hr3.w*x3.y + h47.w*rr.y;
            o3.z = hr3.x*x0.z + hr3.y*x1.z + hr3.z*x2.z + hr3.w*x3.z + h47.w*rr.z;
            o3.w = hr3.x*x0.w + hr3.y*x1.w + hr3.z*x2.w + hr3.w*x3.w + h47.w*rr.w;
            ns_p[768 + idx] = o3;
        }
    }
}

extern "C" void kernel_launch(void* const* d_in, const int* in_sizes, int n_in,
                              void* d_out, int out_size, void* d_ws, size_t ws_size,
                              hipStream_t stream) {
    const float* state    = (const float*)d_in[0];
    const float* residual = (const float*)d_in[1];
    const float* W        = (const float*)d_in[2];
    const float* alpha    = (const float*)d_in[3];
    const float* bias     = (const float*)d_in[4];
    float* out = (float*)d_out;
    // d_ws unused: gates live in LDS; no intermediate global traffic at all.

    hipLaunchKernelGGL(k_fused, dim3(NTOK / 16), dim3(512), 0, stream,
                       state, residual, W, alpha, bias, out);
}